// Round 17
// baseline (53.505 us; speedup 1.0000x reference)
//
#include <hip/hip_runtime.h>
#include <hip/hip_bf16.h>
#include <stdint.h>

typedef __attribute__((ext_vector_type(4))) int i32x4;

#define N_ROWS  32768   // 64 * 512
#define N_CODES 1024
#define DIM     512
#define BK      64      // K-tile (i8 elements = bytes)
#define NT      (DIM / BK)   // 8 K-steps

typedef const __attribute__((address_space(1))) uint32_t guint;
typedef __attribute__((address_space(3))) uint32_t luint;
static __device__ __forceinline__ void gl_lds16(const char* g, char* l) {
    __builtin_amdgcn_global_load_lds((guint*)g, (luint*)l, 16, 0, 0);
}

static __device__ __forceinline__ int q8(float v) {
    int q = __float2int_rn(v * 32.0f);
    return max(-127, min(127, q));
}

// ---------------- K0: quantize X and W to i8 (scale 32) + exact f32 norms ----------------
__global__ void __launch_bounds__(256)
convertXW(const float* __restrict__ X, const float* __restrict__ W,
          char* __restrict__ Xq, char* __restrict__ Wq,
          float* __restrict__ xnorm, float* __restrict__ wnorm) {
    const int lane = threadIdx.x & 63;
    const int sub  = threadIdx.x >> 6;
    const float* src; char* dst; float* nrm; int row;
    if (blockIdx.x < 8192) {
        row = blockIdx.x * 4 + sub;
        src = X; dst = Xq; nrm = xnorm;
    } else {
        row = (blockIdx.x - 8192) * 4 + sub;
        src = W; dst = Wq; nrm = wnorm;
    }
    const float4* p = (const float4*)(src + (size_t)row * DIM + lane * 8);
    float4 a = p[0], b = p[1];
    uint32_t lo = (uint32_t)(q8(a.x) & 0xFF)
                | ((uint32_t)(q8(a.y) & 0xFF) << 8)
                | ((uint32_t)(q8(a.z) & 0xFF) << 16)
                | ((uint32_t)(q8(a.w) & 0xFF) << 24);
    uint32_t hi = (uint32_t)(q8(b.x) & 0xFF)
                | ((uint32_t)(q8(b.y) & 0xFF) << 8)
                | ((uint32_t)(q8(b.z) & 0xFF) << 16)
                | ((uint32_t)(q8(b.w) & 0xFF) << 24);
    *(uint2*)(dst + (size_t)row * DIM + lane * 8) = make_uint2(lo, hi);
    float s = a.x*a.x + a.y*a.y + a.z*a.z + a.w*a.w
            + b.x*b.x + b.y*b.y + b.z*b.z + b.w*b.w;
    #pragma unroll
    for (int d = 1; d < 64; d <<= 1) s += __shfl_xor(s, d);
    if (lane == 0) nrm[row] = s;
}

// ---------------- K1: i8 MFMA GEMM (16x16x64), HIGH-OCCUPANCY 128x128 tile ----------------
// 128x128 tile, BK=64, double-buffer = 32KB LDS total, __launch_bounds__(256,4)
// -> ~4 blocks / 16 waves per CU (2x any prior probe). Cross-block TLP hides
// the per-step barrier/vmcnt exposure that schedule variants couldn't.
// All components verified: 0-conflict geometry (64B rows, 4x16B slots, slot
// XOR (row>>1)&3 both-sides: pre-swizzled source, linear gl_lds dest,
// swizzled read), R7-style stage-first dbuf, XCD row-chunk swizzle
// (colBase = ((bid>>3)&7)*128, rowBase = ((bid&7)*32 + (bid>>6))*128),
// packed-key argmin epilogue, i8 score scale 1/512.
__global__ void __launch_bounds__(256, 4)
gemm_argmin(const char* __restrict__ Xq, const char* __restrict__ Wq,
            const float* __restrict__ wnorm, uint32_t* __restrict__ keys) {
    __shared__ __align__(16) char As[2][128 * BK];   // 16 KB
    __shared__ __align__(16) char Bs[2][128 * BK];   // 16 KB

    const int tid  = threadIdx.x;
    const int lane = tid & 63;
    const int wave = tid >> 6;
    const int wr = wave >> 1, wc = wave & 1;
    const int lr = lane & 15, kg = lane >> 4;

    // bid = xcd + 8*colBlk(0..7) + 64*rowLocal; grid 2048.
    // XCD x owns Xq rows [x*4096, x*4096+4096) = 2MB (L2-resident).
    const int bid = blockIdx.x;
    const int colBase = ((bid >> 3) & 7) * 128;
    const int rowBase = ((bid & 7) * 32 + (bid >> 6)) * 128;

    // staging: thread -> row (tid>>2) and +64, phys slot (tid&3);
    // source slot pre-swizzled by (row>>1)&3 = (tid>>3)&3. LDS dest linear.
    const int ssw = ((tid & 3) ^ ((tid >> 3) & 3)) * 16;
    const char* aS = Xq + (size_t)(rowBase + (tid >> 2)) * DIM + ssw;
    const char* bS = Wq + (size_t)(colBase + (tid >> 2)) * DIM + ssw;

#define STAGE(buf, t) do {                                                    \
    gl_lds16(aS + (t) * BK,           &As[buf][tid * 16]);                    \
    gl_lds16(aS + 64*DIM + (t) * BK,  &As[buf][tid * 16 + 4096]);             \
    gl_lds16(bS + (t) * BK,           &Bs[buf][tid * 16]);                    \
    gl_lds16(bS + 64*DIM + (t) * BK,  &Bs[buf][tid * 16 + 4096]);             \
  } while (0)

    i32x4 acc[4][4];
    #pragma unroll
    for (int m = 0; m < 4; ++m)
        #pragma unroll
        for (int n = 0; n < 4; ++n) acc[m][n] = (i32x4)0;

    const int fq = (kg ^ ((lr >> 1) & 3)) * 16;   // swizzled read slot (bytes)

    STAGE(0, 0);
    __syncthreads();

    #pragma unroll
    for (int t = 0; t < NT; ++t) {
        const int cur = t & 1;
        if (t < NT - 1) STAGE(cur ^ 1, t + 1);   // issue BEFORE reads
        i32x4 aF[4], bF[4];
        #pragma unroll
        for (int m = 0; m < 4; ++m)
            aF[m] = *(const i32x4*)&As[cur][(wr*64 + m*16 + lr) * BK + fq];
        #pragma unroll
        for (int n = 0; n < 4; ++n)
            bF[n] = *(const i32x4*)&Bs[cur][(wc*64 + n*16 + lr) * BK + fq];
        #pragma unroll
        for (int m = 0; m < 4; ++m)
            #pragma unroll
            for (int n = 0; n < 4; ++n)
                acc[m][n] = __builtin_amdgcn_mfma_i32_16x16x64_i8(
                    aF[m], bF[n], acc[m][n], 0, 0, 0);
        __syncthreads();   // drains vmcnt -> next buffer ready
    }
#undef STAGE

    // Epilogue: score = wnorm - acc/512, packed sortable u32 (col in low
    // 10 bits, tie-break = lowest col). One 64-col chunk per (wave, m, r).
    float wn[4]; int wcol[4];
    #pragma unroll
    for (int n = 0; n < 4; ++n) {
        wcol[n] = colBase + wc*64 + n*16 + lr;
        wn[n] = wnorm[wcol[n]];
    }
    const int chunk = (colBase >> 6) + wc;   // 0..15
    #pragma unroll
    for (int m = 0; m < 4; ++m) {
        #pragma unroll
        for (int r = 0; r < 4; ++r) {
            uint32_t best = 0xFFFFFFFFu;
            #pragma unroll
            for (int n = 0; n < 4; ++n) {
                float sc = wn[n] - (float)acc[m][n][r] * 0.001953125f;
                uint32_t u = __float_as_uint(sc);
                u = (u & 0x80000000u) ? ~u : (u | 0x80000000u);  // sortable
                uint32_t key = (u & ~1023u) | (uint32_t)wcol[n];
                best = min(best, key);
            }
            #pragma unroll
            for (int d = 1; d < 16; d <<= 1)
                best = min(best, (uint32_t)__shfl_xor((int)best, d));
            if (lr == 0) {
                const int row = rowBase + wr*64 + m*16 + kg*4 + r;
                keys[(size_t)row * 16 + chunk] = best;
            }
        }
    }
}

// ---------------- K2: min over 16 chunk keys + xnorm -> block partial ----------------
__global__ void __launch_bounds__(256)
reduce_loss(const uint32_t* __restrict__ keys, const float* __restrict__ xnorm,
            float* __restrict__ partial) {
    __shared__ float sm[256];
    const int row = blockIdx.x * 256 + threadIdx.x;
    const uint4* kp = (const uint4*)(keys + (size_t)row * 16);
    uint4 k0 = kp[0], k1 = kp[1], k2 = kp[2], k3 = kp[3];
    uint32_t mk = min(min(min(k0.x, k0.y), min(k0.z, k0.w)),
                      min(min(k1.x, k1.y), min(k1.z, k1.w)));
    mk = min(mk, min(min(min(k2.x, k2.y), min(k2.z, k2.w)),
                     min(min(k3.x, k3.y), min(k3.z, k3.w))));
    uint32_t sb = mk & ~1023u;
    float sc = (sb & 0x80000000u) ? __uint_as_float(sb ^ 0x80000000u)
                                  : __uint_as_float(~sb);
    sm[threadIdx.x] = xnorm[row] + sc;   // ||x||^2 + (||w||^2 - 2 x.w)
    __syncthreads();
    for (int st = 128; st > 0; st >>= 1) {
        if (threadIdx.x < st) sm[threadIdx.x] += sm[threadIdx.x + st];
        __syncthreads();
    }
    if (threadIdx.x == 0) partial[blockIdx.x] = sm[0];
}

// ---------------- K3: final mean over 128 partials (double accum) ----------------
__global__ void __launch_bounds__(128)
finalize(const float* __restrict__ partial, float* __restrict__ out) {
    __shared__ double sm[128];
    sm[threadIdx.x] = (double)partial[threadIdx.x];
    __syncthreads();
    for (int st = 64; st > 0; st >>= 1) {
        if (threadIdx.x < st) sm[threadIdx.x] += sm[threadIdx.x + st];
        __syncthreads();
    }
    if (threadIdx.x == 0)
        out[0] = (float)(sm[0] / (double)((size_t)N_ROWS * DIM));
}

extern "C" void kernel_launch(void* const* d_in, const int* in_sizes, int n_in,
                              void* d_out, int out_size, void* d_ws, size_t ws_size,
                              hipStream_t stream) {
    const float* X = (const float*)d_in[0];   // [32768][512]
    const float* W = (const float*)d_in[1];   // [1024][512]
    char* ws = (char*)d_ws;
    char*     Xq      = ws;                                  // 16 MB @ 0
    char*     Wq      = ws + 16777216;                       // 512 KB
    float*    wnorm   = (float*)(ws + 17301504);             // 4 KB
    float*    xnorm   = (float*)(ws + 17305600);             // 128 KB
    uint32_t* keys    = (uint32_t*)(ws + 17436672);          // 2 MB
    float*    partial = (float*)(ws + 19533824);             // 512 B
    float*    out     = (float*)d_out;

    convertXW<<<8192 + N_CODES / 4, 256, 0, stream>>>(X, W, Xq, Wq, xnorm, wnorm);
    gemm_argmin<<<2048, 256, 0, stream>>>(Xq, Wq, wnorm, keys);
    reduce_loss<<<N_ROWS / 256, 256, 0, stream>>>(keys, xnorm, partial);
    finalize<<<1, 128, 0, stream>>>(partial, out);
}

// Round 18
// 50.409 us; speedup vs baseline: 1.0614x; 1.0614x over previous
//
#include <hip/hip_runtime.h>
#include <hip/hip_bf16.h>
#include <stdint.h>

typedef __attribute__((ext_vector_type(4))) int i32x4;

#define N_ROWS  32768   // 64 * 512
#define N_CODES 1024
#define DIM     512

typedef const __attribute__((address_space(1))) uint32_t guint;
typedef __attribute__((address_space(3))) uint32_t luint;
static __device__ __forceinline__ void gl_lds16(const char* g, char* l) {
    __builtin_amdgcn_global_load_lds((guint*)g, (luint*)l, 16, 0, 0);
}

static __device__ __forceinline__ int q8(float v) {
    int q = __float2int_rn(v * 32.0f);
    return max(-127, min(127, q));
}

// ---------------- K0: quantize X and W to i8 (scale 32) + exact f32 norms ----------------
__global__ void __launch_bounds__(256)
convertXW(const float* __restrict__ X, const float* __restrict__ W,
          char* __restrict__ Xq, char* __restrict__ Wq,
          float* __restrict__ xnorm, float* __restrict__ wnorm) {
    const int lane = threadIdx.x & 63;
    const int sub  = threadIdx.x >> 6;
    const float* src; char* dst; float* nrm; int row;
    if (blockIdx.x < 8192) {
        row = blockIdx.x * 4 + sub;
        src = X; dst = Xq; nrm = xnorm;
    } else {
        row = (blockIdx.x - 8192) * 4 + sub;
        src = W; dst = Wq; nrm = wnorm;
    }
    const float4* p = (const float4*)(src + (size_t)row * DIM + lane * 8);
    float4 a = p[0], b = p[1];
    uint32_t lo = (uint32_t)(q8(a.x) & 0xFF)
                | ((uint32_t)(q8(a.y) & 0xFF) << 8)
                | ((uint32_t)(q8(a.z) & 0xFF) << 16)
                | ((uint32_t)(q8(a.w) & 0xFF) << 24);
    uint32_t hi = (uint32_t)(q8(b.x) & 0xFF)
                | ((uint32_t)(q8(b.y) & 0xFF) << 8)
                | ((uint32_t)(q8(b.z) & 0xFF) << 16)
                | ((uint32_t)(q8(b.w) & 0xFF) << 24);
    *(uint2*)(dst + (size_t)row * DIM + lane * 8) = make_uint2(lo, hi);
    float s = a.x*a.x + a.y*a.y + a.z*a.z + a.w*a.w
            + b.x*b.x + b.y*b.y + b.z*b.z + b.w*b.w;
    #pragma unroll
    for (int d = 1; d < 64; d <<= 1) s += __shfl_xor(s, d);
    if (lane == 0) nrm[row] = s;
}

// ---------------- K1: A-resident, wave-private-B, barrier-free i8 GEMM + full argmin ----------------
// Block = 64 rows x ALL 1024 cols; grid 512 (2 blocks/CU, 56KB LDS).
// Prologue: A (64x512 i8 = 32KB) loaded ONCE into LDS, segment layout
// As[kt][64][64] (each 4KB contiguous -> linear gl_lds dest), slot XOR
// (row>>1)&3 both-sides (verified 0-conflict). One __syncthreads total.
// Loop (64 steps = 8 col-subtiles x 8 K-steps): each wave owns a PRIVATE
// 256-col swath + private 3x2KB B buffer; stages 2KB/step (2 gl_lds),
// counted vmcnt(2), reads resident A (no DMA dep), 8 MFMA. NO barriers,
// no cross-wave coupling -> per-wave latency chains decorrelate.
// Argmin completes in-block (running packed keys, LDS merge) -> no keys
// array, no reduce_loss kernel. XCD row-chunk: XCD x owns rows
// [x*4096,(x+1)*4096) = 2MB Xq (L2-resident); W (512KB) L2-hot everywhere.
__global__ void __launch_bounds__(256, 2)
gemm_argmin(const char* __restrict__ Xq, const char* __restrict__ Wq,
            const float* __restrict__ wnorm, const float* __restrict__ xnorm,
            float* __restrict__ partial) {
    __shared__ __align__(16) char As[8 * 4096];       // 32 KB: [kt][row][slot]
    __shared__ __align__(16) char Bs[4 * 3 * 2048];   // 24 KB: [wave][buf][...]

    const int tid  = threadIdx.x;
    const int lane = tid & 63;
    const int wave = tid >> 6;
    const int lr = lane & 15, kg = lane >> 4;

    // XCD row-chunk swizzle: bid = xcd + 8*rl.
    const int bid = blockIdx.x;
    const int rowBase = ((bid & 7) * 64 + (bid >> 3)) * 64;
    const int colW = wave * 256;                  // wave's private col swath

    // verified slot pre-swizzle: src slot (lane&3) ^ ((row>>1)&3), row=(lane>>2)+16j
    const int ssw = ((lane & 3) ^ ((lane >> 3) & 3)) * 16;
    const char* aS = Xq + (size_t)(rowBase + wave * 16 + (lane >> 2)) * DIM + ssw;
    const char* bS = Wq + (size_t)(colW + (lane >> 2)) * DIM + ssw;
    char* bD = Bs + wave * 6144 + lane * 16;

    // stage B for flat step s: buf=s%3, ct=s>>3 (32-col subtile), kt=s&7
#define STAGE_B(s) do {                                                       \
    const int ct_ = (s) >> 3, kt_ = (s) & 7, buf_ = (s) % 3;                  \
    gl_lds16(bS + (size_t)(ct_ * 32) * DIM + kt_ * 64,      bD + buf_ * 2048);\
    gl_lds16(bS + (size_t)(ct_ * 32 + 16) * DIM + kt_ * 64, bD + buf_ * 2048 + 1024); \
  } while (0)

    // ---- prologue: resident A (8 segments) + B(0), B(1) ----
    #pragma unroll
    for (int kt = 0; kt < 8; ++kt)
        gl_lds16(aS + kt * 64, As + kt * 4096 + wave * 1024 + lane * 16);
    STAGE_B(0);
    STAGE_B(1);
    asm volatile("s_waitcnt vmcnt(2)" ::: "memory");   // A + B(0) landed
    __syncthreads();                                   // A visible to all waves

    i32x4 acc[4][2];
    #pragma unroll
    for (int m = 0; m < 4; ++m) { acc[m][0] = (i32x4)0; acc[m][1] = (i32x4)0; }
    uint32_t runKey[4][4];
    #pragma unroll
    for (int m = 0; m < 4; ++m)
        #pragma unroll
        for (int r = 0; r < 4; ++r) runKey[m][r] = 0xFFFFFFFFu;

    const int fq = (kg ^ ((lr >> 1) & 3)) * 16;   // swizzled read slot (bytes)
    const char* bR = Bs + wave * 6144;

    for (int s = 0; s < 64; ++s) {
        const int kt = s & 7, buf = s % 3;
        i32x4 aF[4], bF[2];
        #pragma unroll
        for (int m = 0; m < 4; ++m)
            aF[m] = *(const i32x4*)&As[kt * 4096 + (m * 16 + lr) * 64 + fq];
        #pragma unroll
        for (int n = 0; n < 2; ++n)
            bF[n] = *(const i32x4*)&bR[buf * 2048 + (n * 16 + lr) * 64 + fq];
        if (s + 2 < 64) STAGE_B(s + 2);           // depth-2, wave-private
        #pragma unroll
        for (int m = 0; m < 4; ++m)
            #pragma unroll
            for (int n = 0; n < 2; ++n)
                acc[m][n] = __builtin_amdgcn_mfma_i32_16x16x64_i8(
                    aF[m], bF[n], acc[m][n], 0, 0, 0);
        if (kt == 7) {   // sub-tile complete: fold scores into running keys
            const int ct = s >> 3;
            #pragma unroll
            for (int n = 0; n < 2; ++n) {
                const int wcol = colW + ct * 32 + n * 16 + lr;
                const float wn = wnorm[wcol];
                #pragma unroll
                for (int m = 0; m < 4; ++m)
                    #pragma unroll
                    for (int r = 0; r < 4; ++r) {
                        float sc = wn - (float)acc[m][n][r] * 0.001953125f;
                        uint32_t u = __float_as_uint(sc);
                        u = (u & 0x80000000u) ? ~u : (u | 0x80000000u);
                        runKey[m][r] = min(runKey[m][r],
                                           (u & ~1023u) | (uint32_t)wcol);
                    }
            }
            #pragma unroll
            for (int m = 0; m < 4; ++m) { acc[m][0] = (i32x4)0; acc[m][1] = (i32x4)0; }
        }
        if (s + 2 < 64)       asm volatile("s_waitcnt vmcnt(2)" ::: "memory");
        else if (s == 62)     asm volatile("s_waitcnt vmcnt(0)" ::: "memory");
    }
#undef STAGE_B

    // ---- per-wave 16-lane col reduce, write per-row key into OWN B region ----
    uint32_t* kbuf = (uint32_t*)(Bs + wave * 6144);   // own region, loop done
    #pragma unroll
    for (int m = 0; m < 4; ++m)
        #pragma unroll
        for (int r = 0; r < 4; ++r) {
            uint32_t k = runKey[m][r];
            #pragma unroll
            for (int d = 1; d < 16; d <<= 1)
                k = min(k, (uint32_t)__shfl_xor((int)k, d));
            if (lr == 0) kbuf[m * 16 + kg * 4 + r] = k;
        }
    __syncthreads();

    // ---- wave 0: merge 4 waves' keys per row, add xnorm, block sum ----
    if (wave == 0) {
        const uint32_t* k0 = (const uint32_t*)(Bs);
        uint32_t k = min(min(k0[lane], k0[1536 + lane]),
                         min(k0[3072 + lane], k0[4608 + lane]));
        uint32_t sb = k & ~1023u;
        float sc = (sb & 0x80000000u) ? __uint_as_float(sb ^ 0x80000000u)
                                      : __uint_as_float(~sb);
        float v = xnorm[rowBase + lane] + sc;
        #pragma unroll
        for (int d = 1; d < 64; d <<= 1) v += __shfl_xor(v, d);
        if (lane == 0) partial[bid] = v;
    }
}

// ---------------- K2: final mean over 512 partials (double accum) ----------------
__global__ void __launch_bounds__(256)
finalize(const float* __restrict__ partial, float* __restrict__ out) {
    __shared__ double sm[256];
    sm[threadIdx.x] = (double)partial[threadIdx.x]
                    + (double)partial[threadIdx.x + 256];
    __syncthreads();
    for (int st = 128; st > 0; st >>= 1) {
        if (threadIdx.x < st) sm[threadIdx.x] += sm[threadIdx.x + st];
        __syncthreads();
    }
    if (threadIdx.x == 0)
        out[0] = (float)(sm[0] / (double)((size_t)N_ROWS * DIM));
}

extern "C" void kernel_launch(void* const* d_in, const int* in_sizes, int n_in,
                              void* d_out, int out_size, void* d_ws, size_t ws_size,
                              hipStream_t stream) {
    const float* X = (const float*)d_in[0];   // [32768][512]
    const float* W = (const float*)d_in[1];   // [1024][512]
    char* ws = (char*)d_ws;
    char*   Xq      = ws;                                  // 16 MB @ 0
    char*   Wq      = ws + 16777216;                       // 512 KB
    float*  wnorm   = (float*)(ws + 17301504);             // 4 KB
    float*  xnorm   = (float*)(ws + 17305600);             // 128 KB
    float*  partial = (float*)(ws + 17436672);             // 2 KB
    float*  out     = (float*)d_out;

    convertXW<<<8192 + N_CODES / 4, 256, 0, stream>>>(X, W, Xq, Wq, xnorm, wnorm);
    gemm_argmin<<<512, 256, 0, stream>>>(Xq, Wq, wnorm, xnorm, partial);
    finalize<<<1, 256, 0, stream>>>(partial, out);
}